// Round 12
// baseline (432.554 us; speedup 1.0000x reference)
//
#include <hip/hip_runtime.h>
#include <hip/hip_bf16.h>
#include <float.h>
#include <limits.h>

// Problem constants (fixed by reference setup_inputs)
#define BATCH 8
#define NN    4096
#define CC    256
#define KNN_K 4
#define NKE   (NN * KNN_K)

// R11 post-mortem: main 206us; pipes VALU 36 / LDS ~45 / MFMA 14% — near-
// serialized phases, LDS largest (each wave re-read the whole 64-row B tile:
// 1KB LDS per MFMA). R12: (1) 2x2 wave grid (32 rows x 32 cols per wave,
// 2 A-frag sets in regs) -> B-frag reused across rt -> 512B LDS per MFMA;
// (2) global_load_lds DMA staging into the padded layout via 33-granule rows
// (pad granule gets a dup; read addressing identical to R11) — no pregs, no
// ds_write instructions; (3) per-lane depth 6, per-(row,wc) top-6 butterfly,
// rescore 12/row/half with the EXACT R1-R5 sequential-fmaf chain (sacred).
#define MTI  64
#define NJ   64
#define NCD  6     // per-lane packed top-k depth == merged width
#define BROW 264   // B-LDS ushort stride (256 + 8 pad) = 528 B = 33 granules
#define NGR  2112  // granules per chunk: 64 rows x 33

typedef __attribute__((ext_vector_type(8))) short  bf16x8;
typedef __attribute__((ext_vector_type(4))) float  f32x4;

// fp32 -> bf16 round-to-nearest-even (inputs finite)
__device__ __forceinline__ short f2bf(float f) {
    unsigned u = __float_as_uint(f);
    return (short)((u + 0x7FFFu + ((u >> 16) & 1u)) >> 16);
}

__device__ __forceinline__ unsigned umin32(unsigned a, unsigned b) { return a < b ? a : b; }
__device__ __forceinline__ unsigned umax32(unsigned a, unsigned b) { return a > b ? a : b; }

// branchless sorted-desc insert into length-6 list
__device__ __forceinline__ void pk_ins6(unsigned k, unsigned (&t)[NCD]) {
    #pragma unroll
    for (int s = NCD - 1; s > 0; --s) t[s] = umax32(t[s], umin32(t[s - 1], k));
    t[0] = umax32(t[0], k);
}

// final-selection predicate matching jax.lax.top_k: value desc, ties -> smaller j
__device__ __forceinline__ bool knn_better(float v, int j, float v2, int j2) {
    return (v > v2) || (v == v2 && j < j2);
}
__device__ __forceinline__ void knn_insert4(float v, int j, float (&tv)[4], int (&tj)[4]) {
    if (knn_better(v, j, tv[3], tj[3])) {
        tv[3] = v; tj[3] = j;
        #pragma unroll
        for (int s = 3; s > 0; --s) {
            if (knn_better(tv[s], tj[s], tv[s - 1], tj[s - 1])) {
                float fv = tv[s]; tv[s] = tv[s - 1]; tv[s - 1] = fv;
                int   fj = tj[s]; tj[s] = tj[s - 1]; tj[s - 1] = fj;
            }
        }
    }
}

// ---------------------------------------------------------------------------
// Kernel 1: per-row inv-norm (+ optional normalized bf16 Xn to ws).
// ---------------------------------------------------------------------------
__global__ void knn_prep_kernel(const float* __restrict__ x, float* __restrict__ invn,
                                ushort* __restrict__ xn, int write_bf16) {
    const int row  = blockIdx.x * 4 + (threadIdx.x >> 6);
    const int lane = threadIdx.x & 63;
    const float4 v = *(const float4*)(x + (size_t)row * CC + lane * 4);
    float ss = v.x * v.x + v.y * v.y + v.z * v.z + v.w * v.w;
    #pragma unroll
    for (int off = 32; off > 0; off >>= 1) ss += __shfl_down(ss, off, 64);
    const float inv = 1.0f / sqrtf(__shfl(ss, 0, 64));
    if (lane == 0) invn[row] = inv;
    if (write_bf16) {
        short4 s4;
        s4.x = f2bf(v.x * inv); s4.y = f2bf(v.y * inv);
        s4.z = f2bf(v.z * inv); s4.w = f2bf(v.w * inv);
        *(short4*)(xn + (size_t)row * CC + lane * 4) = s4;
    }
}

// ---------------------------------------------------------------------------
// Kernel 2: 64 i-rows/block vs a j-range. Wave (wr,wc): rows wr*32+[0,32),
// cols wc*32+[0,32) of each 64-col chunk. Per chunk:
//   barA | global_load_lds DMA (33KB) | barB(vmcnt drain) | 32 MFMA | inserts
// Epilogue: lm-butterfly -> per-(row,wc) top-6 -> in-kernel fp32 rescore
// (EXACT R1-R5 sequential fmaf chain) -> scored pairs to ws (split mode).
// ---------------------------------------------------------------------------
template<bool FROM_BF16>
__global__ __launch_bounds__(256, 3) void knn_main_kernel(
        const float* __restrict__ x, const float* __restrict__ invn,
        const ushort* __restrict__ xn, float* __restrict__ out,
        float* __restrict__ sval, int* __restrict__ sjid, int nh2) {
    __shared__ __align__(16) ushort Bsh[NJ * BROW];   // 33792 B

    const int tid = threadIdx.x;
    const int b   = blockIdx.x & 7;          // batch -> XCD pinning
    const int t   = blockIdx.x >> 3;
    const int it   = nh2 ? (t >> 1) : t;     // i-tile 0..63
    const int half = nh2 ? (t & 1)  : 0;     // j-half
    const int i0   = it * MTI;
    const int jbase = half * (NN / 2);
    const int nch   = nh2 ? (NN / NJ / 2) : (NN / NJ);

    const float*  xb   = x    + (size_t)b * NN * CC;
    const ushort* xnb  = xn   + (size_t)b * NN * CC;
    const float*  invb = invn + (size_t)b * NN;

    const int w  = tid >> 6;                 // wave 0..3
    const int l  = tid & 63;
    const int lm = l & 15;                   // MFMA m/n lane
    const int q  = l >> 4;                   // quad 0..3
    const int wr = w >> 1;                   // row half (rows wr*32..)
    const int wc = w & 1;                    // col half (cols wc*32.. of chunk)

    // ---- A-frags in registers (64 VGPRs); A[m=lane&15][k=quad*8+j] ----
    bf16x8 afrag[2][8];
    #pragma unroll
    for (int rt = 0; rt < 2; ++rt) {
        const int gi = i0 + wr * 32 + rt * 16 + lm;
        if (FROM_BF16) {
            #pragma unroll
            for (int kt = 0; kt < 8; ++kt)
                afrag[rt][kt] = *(const bf16x8*)(xnb + (size_t)gi * CC + kt * 32 + q * 8);
        } else {
            const float vi = invb[gi];
            #pragma unroll
            for (int kt = 0; kt < 8; ++kt) {
                const float* src = xb + (size_t)gi * CC + kt * 32 + q * 8;
                const float4 f0 = *(const float4*)(src);
                const float4 f1 = *(const float4*)(src + 4);
                bf16x8 a;
                a[0] = f2bf(f0.x * vi); a[1] = f2bf(f0.y * vi);
                a[2] = f2bf(f0.z * vi); a[3] = f2bf(f0.w * vi);
                a[4] = f2bf(f1.x * vi); a[5] = f2bf(f1.y * vi);
                a[6] = f2bf(f1.z * vi); a[7] = f2bf(f1.w * vi);
                afrag[rt][kt] = a;
            }
        }
    }

    // per-lane packed top-6 lists; list li = rt*4+reg -> row wr*32+rt*16+q*4+reg
    unsigned cl[8][NCD];
    #pragma unroll
    for (int li = 0; li < 8; ++li)
        #pragma unroll
        for (int s = 0; s < NCD; ++s) cl[li][s] = 0u;

    // DMA granule decomposition: G = lp*256 + tid -> row G/33, granule G%33
    const int r0 = (tid * 993) >> 15;        // tid/33 for tid<256
    const int c0 = tid - r0 * 33;

    for (int jt = 0; jt < nch; ++jt) {
        const int j0 = jbase + jt * NJ;
        __syncthreads();                      // (A) all Bsh readers done
        if (FROM_BF16) {
            int r = r0, c = c0;               // row/granule for G = tid
            #pragma unroll
            for (int lp = 0; lp < 9; ++lp) {
                if (lp < 8 || w == 0) {       // wave-uniform tail mask (G < 2112)
                    const int cc2 = (c == 32) ? 0 : c;   // pad granule: dup g0
                    const ushort* src = xnb + (size_t)(j0 + r) * CC + cc2 * 8;
                    ushort* dst = Bsh + (lp * 2048 + w * 512);   // uniform wave base
                    __builtin_amdgcn_global_load_lds(
                        (const __attribute__((address_space(1))) unsigned int*)src,
                        (__attribute__((address_space(3))) unsigned int*)dst,
                        16, 0, 0);
                }
                // advance G by 256: rows +7, granules +25 (256 = 7*33 + 25)
                c += 25; r += 7;
                if (c >= 33) { c -= 33; ++r; }
            }
        } else {
            #pragma unroll
            for (int lp = 0; lp < 16; ++lp) {
                const int u2 = tid + 256 * lp;
                const int row = u2 >> 6, c4 = u2 & 63;
                const float sc = invb[j0 + row];
                const float4 v = *(const float4*)(xb + (size_t)(j0 + row) * CC + c4 * 4);
                short4 s4;
                s4.x = f2bf(v.x * sc); s4.y = f2bf(v.y * sc);
                s4.z = f2bf(v.z * sc); s4.w = f2bf(v.w * sc);
                *(short4*)(Bsh + row * BROW + c4 * 4) = s4;
            }
        }
        __syncthreads();                      // (B) DMA/stores drained (vmcnt 0)

        // ---- MFMA: B-frag read once, reused across 2 rt ----
        f32x4 acc[2][2];
        #pragma unroll
        for (int rt = 0; rt < 2; ++rt)
            #pragma unroll
            for (int ct = 0; ct < 2; ++ct) acc[rt][ct] = (f32x4){0.f, 0.f, 0.f, 0.f};
        #pragma unroll
        for (int kt = 0; kt < 8; ++kt) {
            bf16x8 bf[2];
            #pragma unroll
            for (int ct = 0; ct < 2; ++ct)
                bf[ct] = *(const bf16x8*)(Bsh + (wc * 32 + ct * 16 + lm) * BROW + kt * 32 + q * 8);
            #pragma unroll
            for (int rt = 0; rt < 2; ++rt)
                #pragma unroll
                for (int ct = 0; ct < 2; ++ct)
                    acc[rt][ct] = __builtin_amdgcn_mfma_f32_16x16x32_bf16(
                        afrag[rt][kt], bf[ct], acc[rt][ct], 0, 0, 0);
        }

        // ---- pack + branchless insert ----
        // key = bits(sim+2.0) top-20 (monotone, ULP~3e-5); low-12 = 4095-j
        const bool dchunk = (j0 == i0);
        #pragma unroll
        for (int ct = 0; ct < 2; ++ct) {
            const int jl  = wc * 32 + ct * 16 + lm;    // col within tile
            const unsigned ivj = (unsigned)(4095 - (j0 + jl));
            #pragma unroll
            for (int rt = 0; rt < 2; ++rt)
                #pragma unroll
                for (int reg = 0; reg < 4; ++reg) {
                    const int rl = wr * 32 + rt * 16 + q * 4 + reg;   // row within tile
                    unsigned pk = (__float_as_uint(acc[rt][ct][reg] + 2.0f) & 0xFFFFF000u) | ivj;
                    if (dchunk && rl == jl) pk = 0u;   // self
                    pk_ins6(pk, cl[rt * 4 + reg]);
                }
        }
    }

    // ---- butterfly merge across the 16 lm-lanes (in place) ----
    #pragma unroll
    for (int m = 1; m <= 8; m <<= 1) {
        #pragma unroll
        for (int li = 0; li < 8; ++li) {
            unsigned pin[NCD];
            #pragma unroll
            for (int s = 0; s < NCD; ++s)
                pin[s] = (unsigned)__shfl_xor((int)cl[li][s], m, 64);
            #pragma unroll
            for (int s = 0; s < NCD; ++s) pk_ins6(pin[s], cl[li]);
        }
    }

    // ---- stash per-(row, wc) top-6 into LDS: cpk[row][wc*6+s] ----
    unsigned* cpk = (unsigned*)Bsh;              // [64][12] packed (3 KB)
    __syncthreads();                             // all kt-loop readers done
    if (lm == 0) {
        #pragma unroll
        for (int li = 0; li < 8; ++li) {
            const int rl = wr * 32 + (li >> 2) * 16 + q * 4 + (li & 3);
            #pragma unroll
            for (int s = 0; s < NCD; ++s) cpk[rl * 12 + wc * 6 + s] = cl[li][s];
        }
    }
    __syncthreads();

    // ---- in-kernel fp32 rescore: EXACT R1-R5 sequential-fmaf chain ----
    // thread t: row = t&63, slot = t>>6 -> cands slot*3..slot*3+2 of 12
    const int rr   = tid & 63;
    const int slot = tid >> 6;
    const int ig   = i0 + rr;
    const float inv_i = invb[ig];
    const float* xi = xb + (size_t)ig * CC;
    float rv[3]; int rj[3];
    #pragma unroll
    for (int u = 0; u < 3; ++u) {
        const int c  = slot * 3 + u;
        const int jc = 4095 - (int)(cpk[rr * 12 + c] & 0xFFFu);
        const float* xj = xb + (size_t)jc * CC;
        float d = 0.f;
        #pragma unroll 16
        for (int k4 = 0; k4 < 64; ++k4) {
            const float4 av = *(const float4*)(xi + k4 * 4);
            const float4 bv = *(const float4*)(xj + k4 * 4);
            d = fmaf(av.x, bv.x, d);
            d = fmaf(av.y, bv.y, d);
            d = fmaf(av.z, bv.z, d);
            d = fmaf(av.w, bv.w, d);
        }
        rv[u] = d * inv_i * invb[jc];
        rj[u] = jc;
    }

    if (nh2) {
        #pragma unroll
        for (int u = 0; u < 3; ++u) {
            const size_t o = ((size_t)(b * NN + ig) * 2 + half) * 12 + (slot * 3 + u);
            sval[o] = rv[u];
            sjid[o] = rj[u];
        }
        return;
    }

    // full-j mode: select top-4 of 12 in-block
    float* cvl = (float*)(Bsh + 2048);           // byte 4096: [64][12] fp32
    #pragma unroll
    for (int u = 0; u < 3; ++u) cvl[rr * 12 + slot * 3 + u] = rv[u];
    __syncthreads();
    if (tid < MTI) {
        const int r = tid, ig2 = i0 + r;
        float fv[4]; int fj[4];
        #pragma unroll
        for (int s = 0; s < 4; ++s) { fv[s] = -INFINITY; fj[s] = INT_MAX; }
        for (int c = 0; c < 12; ++c) {
            const int jc = 4095 - (int)(cpk[r * 12 + c] & 0xFFFu);
            knn_insert4(cvl[r * 12 + c], jc, fv, fj);
        }
        float* o_src = out + (size_t)b * 2 * NKE;
        float* o_tgt = o_src + NKE;
        float* o_w   = out + (size_t)BATCH * 2 * NKE + (size_t)b * NKE;
        #pragma unroll
        for (int s = 0; s < 4; ++s) {
            o_src[ig2 * KNN_K + s] = (float)ig2;
            o_tgt[ig2 * KNN_K + s] = (float)fj[s];
            o_w[ig2 * KNN_K + s]   = fv[s];
        }
    }
}

// ---------------------------------------------------------------------------
// Kernel 3 (split mode): top-4 of 24 pre-scored (val,j) pairs per row.
// ---------------------------------------------------------------------------
__global__ __launch_bounds__(256) void knn_select_kernel(
        const float* __restrict__ sval, const int* __restrict__ sjid,
        float* __restrict__ out) {
    const int row_g = blockIdx.x * 256 + threadIdx.x;   // 0..32767
    const int bb = row_g >> 12, ig = row_g & (NN - 1);
    float fv[4]; int fj[4];
    #pragma unroll
    for (int s = 0; s < 4; ++s) { fv[s] = -INFINITY; fj[s] = INT_MAX; }
    const size_t base = (size_t)row_g * 24;
    for (int c = 0; c < 24; ++c)
        knn_insert4(sval[base + c], sjid[base + c], fv, fj);
    float* o_src = out + (size_t)bb * 2 * NKE;
    float* o_tgt = o_src + NKE;
    float* o_w   = out + (size_t)BATCH * 2 * NKE + (size_t)bb * NKE;
    #pragma unroll
    for (int s = 0; s < 4; ++s) {
        o_src[ig * KNN_K + s] = (float)ig;
        o_tgt[ig * KNN_K + s] = (float)fj[s];
        o_w[ig * KNN_K + s]   = fv[s];
    }
}

extern "C" void kernel_launch(void* const* d_in, const int* in_sizes, int n_in,
                              void* d_out, int out_size, void* d_ws, size_t ws_size,
                              hipStream_t stream) {
    const float* x    = (const float*)d_in[0];
    float*       out  = (float*)d_out;
    float*       invn = (float*)d_ws;                                   // 128 KB
    ushort*      xn   = (ushort*)((char*)d_ws + 131072);                // 16.78 MB
    char*        p2   = (char*)d_ws + 131072 + (size_t)BATCH * NN * CC * sizeof(ushort);
    float*       sval = (float*)p2;                                     // 3.15 MB
    int*         sjid = (int*)(p2 + (size_t)BATCH * NN * 24 * sizeof(float));
    const size_t need_xn  = 131072 + (size_t)BATCH * NN * CC * sizeof(ushort);
    const size_t need_all = need_xn + (size_t)BATCH * NN * 24 * 8;

    if (ws_size >= need_all) {
        knn_prep_kernel<<<(BATCH * NN) / 4, 256, 0, stream>>>(x, invn, xn, 1);
        knn_main_kernel<true><<<BATCH * MTI * 2, 256, 0, stream>>>(x, invn, xn, out, sval, sjid, 1);
        knn_select_kernel<<<(BATCH * NN) / 256, 256, 0, stream>>>(sval, sjid, out);
    } else if (ws_size >= need_xn) {
        knn_prep_kernel<<<(BATCH * NN) / 4, 256, 0, stream>>>(x, invn, xn, 1);
        knn_main_kernel<true><<<BATCH * MTI, 256, 0, stream>>>(x, invn, xn, out, nullptr, nullptr, 0);
    } else {
        knn_prep_kernel<<<(BATCH * NN) / 4, 256, 0, stream>>>(x, invn, xn, 0);
        knn_main_kernel<false><<<BATCH * MTI, 256, 0, stream>>>(x, invn, xn, out, nullptr, nullptr, 0);
    }
}